// Round 13
// baseline (113.676 us; speedup 1.0000x reference)
//
#include <hip/hip_runtime.h>
#include <stdint.h>

#define SEQ   2048
#define DEMB  1024
#define NH    16
#define HD    64
#define MROWS 4096   // BS*SEQ

typedef __bf16 bf16x8 __attribute__((ext_vector_type(8)));
typedef __bf16 bf16x4 __attribute__((ext_vector_type(4)));
typedef float  f32x4  __attribute__((ext_vector_type(4)));

#define MFMA(a, b, c) __builtin_amdgcn_mfma_f32_16x16x32_bf16((a), (b), (c), 0, 0, 0)
#define VMCNT(n) asm volatile("s_waitcnt vmcnt(" #n ")" ::: "memory")

static __device__ __forceinline__ uint16_t f2bf(float f) {
  union { __bf16 b; uint16_t u; } c;
  c.b = (__bf16)f;
  return c.u;
}

static __device__ __forceinline__ ushort4 pack4(f32x4 f) {
  union { bf16x4 b; ushort4 u; } c;
  c.b[0] = (__bf16)f[0]; c.b[1] = (__bf16)f[1];
  c.b[2] = (__bf16)f[2]; c.b[3] = (__bf16)f[3];
  return c.u;
}

static __device__ __forceinline__ bf16x8 ldb8(const uint16_t* p) {
  union { uint4 i; bf16x8 b; } u;
  u.i = *(const uint4*)p;
  return u.b;
}

static __device__ __forceinline__ void gld_lds16(const uint16_t* g, uint16_t* l) {
  __builtin_amdgcn_global_load_lds(
      (const __attribute__((address_space(1))) uint32_t*)(g),
      (__attribute__((address_space(3))) uint32_t*)(l),
      16, 0, 0);
}

// ---------------------------------------------------------------- fused converts
__global__ __launch_bounds__(256) void cvt_all(const float* __restrict__ x,
                                               const float* __restrict__ wq,
                                               const float* __restrict__ wk,
                                               const float* __restrict__ wv,
                                               const float* __restrict__ wo,
                                               uint16_t* __restrict__ xb,
                                               uint16_t* __restrict__ wqkv,
                                               uint16_t* __restrict__ wob) {
  const int bid = blockIdx.x;
  const float* src; uint16_t* dst; int off;
  if (bid < 4096)      { src = x;  dst = xb;                 off = bid; }
  else if (bid < 5120) { src = wq; dst = wqkv;               off = bid - 4096; }
  else if (bid < 6144) { src = wk; dst = wqkv + (1u << 20);  off = bid - 5120; }
  else if (bid < 7168) { src = wv; dst = wqkv + (2u << 20);  off = bid - 6144; }
  else                 { src = wo; dst = wob;                off = bid - 7168; }
  const int i = (off * 256 + threadIdx.x) * 4;
  float4 v = *(const float4*)(src + i);
  f32x4 f; f[0] = v.x; f[1] = v.y; f[2] = v.z; f[3] = v.w;
  *(ushort4*)(dst + i) = pack4(f);
}

// ---------------------------------------------------------------- QKV GEMM
// 256x192, BK=64, 512 thr (8 waves 2Mx4N, wave 128x48), grid 16x16 = 1/CU.
// R12 buffering kept (A triple @0/16384/32768, B double @49152/61440; end-of-
// tile vmcnt(4), raw barriers). NEW R13: 4-PHASE INTERLEAVED BODY (m196/m201
// lever): each phase = {1-2 staging issues; ds_read one quadrant; s_barrier;
// setprio+12 MFMA+setprio; s_barrier}. Staging issue order per tile t:
// B(t+1) L1,L2 | B L3 + A(t+2) L1 | A L2,L3 | A L4 -> FIFO: end-of-tile
// vmcnt(4) leaves exactly A(t+2)'s 4 in flight.
__global__ __launch_bounds__(512, 2) void gemm_qkv(const uint16_t* __restrict__ A,
                                                   const uint16_t* __restrict__ B,
                                                   uint16_t* __restrict__ Cq,
                                                   uint16_t* __restrict__ Ck,
                                                   uint16_t* __restrict__ Cvt) {
  constexpr int K = 1024;
  __shared__ uint16_t lds[73728];      // 144 KB

  const int bcol = blockIdx.x * 192;
  const int brow = blockIdx.y << 8;

  const int t  = threadIdx.x;
  const int l  = t & 63;
  const int li = l & 15, lg = l >> 4;
  const int w  = t >> 6;               // 0..7
  const int wm = w >> 2;               // row half: wm*128
  const int wn = w & 3;                // col quarter: wn*48

  const int srow = t >> 3;
  const int scol = ((t & 7) ^ (srow & 7)) << 3;
  const uint16_t* gA = A + (size_t)(brow + srow) * K + scol;
  const uint16_t* gB = B + (size_t)(bcol + srow) * K + scol;

  auto stA = [&](int buf, int k0, int i) {       // one of 4 A loads
    gld_lds16(gA + (size_t)(i * 64) * K + k0, lds + buf * 16384 + i * 4096 + t * 8);
  };
  auto stB = [&](int buf, int k0, int i) {       // one of 3 B loads
    gld_lds16(gB + (size_t)(i * 64) * K + k0, lds + 49152 + buf * 12288 + i * 4096 + t * 8);
  };

  const int sw = li & 7;
  auto ldA = [&](int buf, int kh, int fi) {
    const int row = wm * 128 + fi * 16 + li;
    return ldb8(&lds[buf * 16384 + (row << 6) + ((((kh << 2) + lg) ^ sw) << 3)]);
  };
  auto ldB = [&](int buf, int kh, int ni) {
    const int row = wn * 48 + ni * 16 + li;
    return ldb8(&lds[49152 + buf * 12288 + (row << 6) + ((((kh << 2) + lg) ^ sw) << 3)]);
  };

  f32x4 acc[8][3] = {};

  // prologue: B(0), A(0), A(1) -> wait all but A(1)'s 4 loads
  stB(0, 0, 0); stB(0, 0, 1); stB(0, 0, 2);
  stA(0, 0, 0); stA(0, 0, 1); stA(0, 0, 2); stA(0, 0, 3);
  stA(1, 64, 0); stA(1, 64, 1); stA(1, 64, 2); stA(1, 64, 3);
  VMCNT(4);
  __builtin_amdgcn_s_barrier();

  for (int kt = 0; kt < 16; ++kt) {
    const int k0 = kt << 6;
    const int ab = kt % 3, bb = kt & 1;
    const int nbA = (kt + 2) % 3, nbB = (kt + 1) & 1;
    const bool pB = (kt + 1 < 16), pA = (kt + 2 < 16);
    bf16x8 af[4], b0[3], b1[3];

    // ---- phase 1: kh0 x fi0-3
    if (pB) { stB(nbB, k0 + 64, 0); stB(nbB, k0 + 64, 1); }
#pragma unroll
    for (int ni = 0; ni < 3; ++ni) b0[ni] = ldB(bb, 0, ni);
#pragma unroll
    for (int fi = 0; fi < 4; ++fi) af[fi] = ldA(ab, 0, fi);
    __builtin_amdgcn_s_barrier();
    __builtin_amdgcn_s_setprio(1);
#pragma unroll
    for (int fi = 0; fi < 4; ++fi)
#pragma unroll
      for (int ni = 0; ni < 3; ++ni)
        acc[fi][ni] = MFMA(af[fi], b0[ni], acc[fi][ni]);
    __builtin_amdgcn_s_setprio(0);
    __builtin_amdgcn_s_barrier();

    // ---- phase 2: kh0 x fi4-7
    if (pB) stB(nbB, k0 + 64, 2);
    if (pA) stA(nbA, k0 + 128, 0);
#pragma unroll
    for (int fi = 0; fi < 4; ++fi) af[fi] = ldA(ab, 0, 4 + fi);
    __builtin_amdgcn_s_barrier();
    __builtin_amdgcn_s_setprio(1);
#pragma unroll
    for (int fi = 0; fi < 4; ++fi)
#pragma unroll
      for (int ni = 0; ni < 3; ++ni)
        acc[4 + fi][ni] = MFMA(af[fi], b0[ni], acc[4 + fi][ni]);
    __builtin_amdgcn_s_setprio(0);
    __builtin_amdgcn_s_barrier();

    // ---- phase 3: kh1 x fi0-3
    if (pA) { stA(nbA, k0 + 128, 1); stA(nbA, k0 + 128, 2); }
#pragma unroll
    for (int ni = 0; ni < 3; ++ni) b1[ni] = ldB(bb, 1, ni);
#pragma unroll
    for (int fi = 0; fi < 4; ++fi) af[fi] = ldA(ab, 1, fi);
    __builtin_amdgcn_s_barrier();
    __builtin_amdgcn_s_setprio(1);
#pragma unroll
    for (int fi = 0; fi < 4; ++fi)
#pragma unroll
      for (int ni = 0; ni < 3; ++ni)
        acc[fi][ni] = MFMA(af[fi], b1[ni], acc[fi][ni]);
    __builtin_amdgcn_s_setprio(0);
    __builtin_amdgcn_s_barrier();

    // ---- phase 4: kh1 x fi4-7
    if (pA) stA(nbA, k0 + 128, 3);
#pragma unroll
    for (int fi = 0; fi < 4; ++fi) af[fi] = ldA(ab, 1, 4 + fi);
    __builtin_amdgcn_s_barrier();
    __builtin_amdgcn_s_setprio(1);
#pragma unroll
    for (int fi = 0; fi < 4; ++fi)
#pragma unroll
      for (int ni = 0; ni < 3; ++ni)
        acc[4 + fi][ni] = MFMA(af[fi], b1[ni], acc[4 + fi][ni]);
    __builtin_amdgcn_s_setprio(0);

    if (kt + 1 < 16) {
      if (pA) VMCNT(4);            // A(t+1)+B(t+1) landed; A(t+2) in flight
      else    VMCNT(0);            // tail drain
    }
    __builtin_amdgcn_s_barrier();
  }

  __syncthreads();                 // protect LDS reuse by the V-transpose slab

  // ---- epilogue. Q/K: direct stores. V: per-wave LDS transpose -> coalesced.
  uint16_t* slab = lds + w * 6800;
  bool anyV = false;

#pragma unroll
  for (int mi = 0; mi < 8; ++mi) {
#pragma unroll
    for (int ni = 0; ni < 3; ++ni) {
      const int col = bcol + wn * 48 + ni * 16 + li;
      const int row = brow + wm * 128 + mi * 16 + lg * 4;   // + r
      if (col < 1024) {
#pragma unroll
        for (int r = 0; r < 4; ++r)
          Cq[(size_t)(row + r) * 1024 + col] = f2bf(acc[mi][ni][r] * 0.18033688f);
      } else if (col < 2048) {
#pragma unroll
        for (int r = 0; r < 4; ++r)
          Ck[(size_t)(row + r) * 1024 + (col - 1024)] = f2bf(acc[mi][ni][r]);
      } else {
        anyV = true;
        *(ushort4*)&slab[(ni * 16 + li) * 136 + mi * 16 + lg * 4] = pack4(acc[mi][ni]);
      }
    }
  }

  if (anyV) {
    asm volatile("s_waitcnt lgkmcnt(0)" ::: "memory");
    const int m0 = brow + wm * 128;
    const size_t mbase = (size_t)((m0 >> 11) << 10) * 2048 + (m0 & 2047);
#pragma unroll
    for (int cc = 0; cc < 12; ++cc) {
      const int c_loc = cc * 4 + lg;
      const int cglob = bcol + wn * 48 + c_loc;
      if (cglob >= 2048) {
        const int c = cglob - 2048;
        uint4 v = *(const uint4*)&slab[c_loc * 136 + li * 8];
        *(uint4*)(Cvt + (size_t)c * 2048 + mbase + li * 8) = v;
      }
    }
  }
}

// ---------------------------------------------------------------- out projection
// (R12 version: 128x128, 8 waves, triple-buffer depth-2, counted vmcnt)
__global__ __launch_bounds__(512, 2) void gemm_out(const uint16_t* __restrict__ A,
                                                   const uint16_t* __restrict__ B,
                                                   float* __restrict__ Cf,
                                                   const float* __restrict__ bias) {
  constexpr int K = 1024;
  __shared__ uint16_t lds[49152];      // 96 KB

  const int bcol = blockIdx.x << 7;
  const int brow = blockIdx.y << 7;

  const int t  = threadIdx.x;
  const int l  = t & 63;
  const int li = l & 15, lg = l >> 4;
  const int w  = t >> 6;
  const int wm = w >> 2;
  const int wn = w & 3;

  const int srow = t >> 3;
  const int scol = ((t & 7) ^ (srow & 7)) << 3;
  const uint16_t* gA = A + (size_t)(brow + srow) * K + scol;
  const uint16_t* gB = B + (size_t)(bcol + srow) * K + scol;

  auto stage = [&](int buf, int k0) {            // 4 loads
    uint16_t* as = lds + buf * 8192;
    uint16_t* bs = lds + 24576 + buf * 8192;
    gld_lds16(gA + k0,                  as + t * 8);
    gld_lds16(gA + (size_t)64 * K + k0, as + 4096 + t * 8);
    gld_lds16(gB + k0,                  bs + t * 8);
    gld_lds16(gB + (size_t)64 * K + k0, bs + 4096 + t * 8);
  };

  const int sw = li & 7;
  auto ldA = [&](int buf, int kh, int fi) {
    const int row = wm * 64 + fi * 16 + li;
    return ldb8(&lds[buf * 8192 + (row << 6) + ((((kh << 2) + lg) ^ sw) << 3)]);
  };
  auto ldB = [&](int buf, int kh, int ni) {
    const int row = wn * 32 + ni * 16 + li;
    return ldb8(&lds[24576 + buf * 8192 + (row << 6) + ((((kh << 2) + lg) ^ sw) << 3)]);
  };

  f32x4 acc[4][2] = {};

  stage(0, 0);
  stage(1, 64);
  VMCNT(4);
  __builtin_amdgcn_s_barrier();

  for (int kt = 0; kt < 16; ++kt) {
    const int k0 = kt << 6;
    if (kt + 2 < 16) stage((kt + 2) % 3, k0 + 128);

    const int cb = kt % 3;
#pragma unroll
    for (int kh = 0; kh < 2; ++kh) {
      bf16x8 af[4], bfr[2];
#pragma unroll
      for (int ni = 0; ni < 2; ++ni) bfr[ni] = ldB(cb, kh, ni);
#pragma unroll
      for (int fi = 0; fi < 4; ++fi) af[fi] = ldA(cb, kh, fi);
      __builtin_amdgcn_s_setprio(1);
#pragma unroll
      for (int fi = 0; fi < 4; ++fi)
#pragma unroll
        for (int ni = 0; ni < 2; ++ni)
          acc[fi][ni] = MFMA(af[fi], bfr[ni], acc[fi][ni]);
      __builtin_amdgcn_s_setprio(0);
    }

    if (kt + 1 < 16) {
      if (kt + 2 < 16) VMCNT(4);
      else             VMCNT(0);
      __builtin_amdgcn_s_barrier();
    }
  }

#pragma unroll
  for (int mi = 0; mi < 4; ++mi) {
#pragma unroll
    for (int ni = 0; ni < 2; ++ni) {
      const int row = brow + wm * 64 + mi * 16 + lg * 4;
      const int col = bcol + wn * 32 + ni * 16 + li;
      const float bv = bias[col];
#pragma unroll
      for (int r = 0; r < 4; ++r)
        Cf[(size_t)(row + r) * 1024 + col] = acc[mi][ni][r] + bv;
    }
  }
}

// ---------------------------------------------------------------- flash attention
// R12 skeleton (4-wave, QBLK=64, causal-paired 512 blocks, triple-buffered K/V,
// no-max exp2 softmax) + R13 QK-ONE-TILE-AHEAD (T15-lite): QK(t+1) computed
// between Pwrite(t) and Pread(t), filling the ds_write->ds_read gap and
// removing QK from the head of the per-tile chain. Mid-iter vmcnt(4) (after
// stage(t+2) issue) guarantees K(t+1) landed; end-of-iter raw barrier only.
__global__ __launch_bounds__(256, 2) void attn_fwd(const uint16_t* __restrict__ Q,
                                                   const uint16_t* __restrict__ K,
                                                   const uint16_t* __restrict__ Vt,
                                                   uint16_t* __restrict__ ctx) {
  const int id   = blockIdx.x;
  const int rank = id >> 3;                  // 0..63
  const int bh   = (id & 7) * 4 + (rank >> 4);
  const int pr   = rank & 15;                // pair index 0..15
  const int b = bh >> 4, h = bh & 15;

  const int t  = threadIdx.x;
  const int w  = t >> 6, l = t & 63;
  const int li = l & 15, lg = l >> 4;

  __shared__ uint16_t Kl[3][64 * 64];   // 24 KB (key, d) swizzled
  __shared__ uint16_t Vl[3][64 * 64];   // 24 KB (d, key) swizzled
  __shared__ uint16_t P[4][16][72];     // 9 KB per-wave P slab

  const uint16_t* Kg = K + (size_t)(b * 2048) * 1024 + h * 64;
  const uint16_t* Vg = Vt + (size_t)(b * 1024 + h * 64) * 2048;

  const int srow = t >> 3;                          // 0..31
  const int scol = ((t & 7) * 8) ^ ((srow & 7) * 8);

  auto stage = [&](int buf, int kt2) {              // 4 loads
    const int kb2 = kt2 << 6;
    gld_lds16(Kg + (size_t)(kb2 + srow) * 1024 + scol,      &Kl[buf][t * 8]);
    gld_lds16(Kg + (size_t)(kb2 + 32 + srow) * 1024 + scol, &Kl[buf][2048 + t * 8]);
    gld_lds16(Vg + (size_t)srow * 2048 + kb2 + scol,        &Vl[buf][t * 8]);
    gld_lds16(Vg + (size_t)(32 + srow) * 2048 + kb2 + scol, &Vl[buf][2048 + t * 8]);
  };

  const int fsw = (li & 7) * 8;

#pragma unroll 1
  for (int ph = 0; ph < 2; ++ph) {
    const int qbl  = ph ? (31 - pr) : pr;
    const int nkt  = qbl + 1;
    const int qrow = (qbl << 6) + (w << 4);
    const uint16_t* qp = Q + (size_t)(b * 2048 + qrow + li) * 1024 + h * 64 + lg * 8;
    const bf16x8 q0 = ldb8(qp);
    const bf16x8 q1 = ldb8(qp + 32);

    f32x4 o[4] = {};
    float l_r = 0.f;

    stage(0, 0);
    stage(1, 1);                   // tile-1 prefetch (in-bounds: keys 64..127)
    VMCNT(4);                      // tile-0 landed; tile-1 in flight
    __builtin_amdgcn_s_barrier();

    // prologue: QK(0)
    f32x4 s_cur[4];
    {
      const uint16_t* Kc = &Kl[0][0];
#pragma unroll
      for (int tt = 0; tt < 4; ++tt) {
        const uint16_t* kr = Kc + (tt * 16 + li) * 64;
        f32x4 z = {};
        z = MFMA(ldb8(kr + ((lg * 8) ^ fsw)), q0, z);
        z = MFMA(ldb8(kr + ((32 + lg * 8) ^ fsw)), q1, z);
        s_cur[tt] = z;
      }
    }

    for (int kt = 0; kt < nkt; ++kt) {
      if (kt + 2 < nkt) stage((kt + 2) % 3, kt + 2);

      // V fragments of tile kt
      const uint16_t* Vc = &Vl[kt % 3][0];
      bf16x8 vf[4][2];
#pragma unroll
      for (int dt = 0; dt < 4; ++dt) {
        const uint16_t* vr = Vc + (dt * 16 + li) * 64;
        vf[dt][0] = ldb8(vr + ((lg * 8) ^ fsw));
        vf[dt][1] = ldb8(vr + ((32 + lg * 8) ^ fsw));
      }

      if (kt == qbl) {             // diagonal: causal mask -> exp2 -> 0
        const int qloc = (w << 4) + li;
#pragma unroll
        for (int tt = 0; tt < 4; ++tt) {
          const int key = (tt << 4) + (lg << 2);
#pragma unroll
          for (int r = 0; r < 4; ++r)
            if (key + r > qloc) s_cur[tt][r] = -1e30f;
        }
      }

      // ---- no-max softmax on s_cur: P = exp2(s), per-lane partial l
      float lsum = 0.f;
      ushort4 pk[4];
#pragma unroll
      for (int tt = 0; tt < 4; ++tt) {
        f32x4 p;
        p[0] = __builtin_amdgcn_exp2f(s_cur[tt][0]);
        p[1] = __builtin_amdgcn_exp2f(s_cur[tt][1]);
        p[2] = __builtin_amdgcn_exp2f(s_cur[tt][2]);
        p[3] = __builtin_amdgcn_exp2f(s_cur[tt][3]);
        lsum += (p[0] + p[1]) + (p[2] + p[3]);
        pk[tt] = pack4(p);
      }
      l_r += lsum;

      // ---- P write
#pragma unroll
      for (int tt = 0; tt < 4; ++tt)
        *(ushort4*)&P[w][li][(tt << 4) + (lg << 2)] = pk[tt];

      // ---- QK(t+1) fills the Pwrite->Pread gap (K(t+1) landed after vmcnt)
      f32x4 s_nx[4];
      if (kt + 1 < nkt) {
        if (kt + 2 < nkt) VMCNT(4);    // stage(t+1) landed; stage(t+2) in flight
        else              VMCNT(0);
        const uint16_t* Kc = &Kl[(kt + 1) % 3][0];
        __builtin_amdgcn_s_setprio(1);
#pragma unroll
        for (int tt = 0; tt < 4; ++tt) {
          const uint16_t* kr = Kc + (tt * 16 + li) * 64;
          f32x4 z = {};
          z = MFMA(ldb8(kr + ((lg * 8) ^ fsw)), q0, z);
          z = MFMA(ldb8(kr + ((32 + lg * 8) ^ fsw)), q1, z);
          s_nx[tt] = z;
        }
        __builtin_amdgcn_s_setprio(0);
      }

      // ---- P read + PV
      asm volatile("s_waitcnt lgkmcnt(0)" ::: "memory");
      const bf16x8 pb0 = ldb8(&P[w][li][lg * 8]);
      const bf16x8 pb1 = ldb8(&P[w][li][32 + lg * 8]);
      __builtin_amdgcn_s_setprio(1);
#pragma unroll
      for (int dt = 0; dt < 4; ++dt) {
        o[dt] = MFMA(vf[dt][0], pb0, o[dt]);
        o[dt] = MFMA(vf[dt][1], pb1, o[dt]);
      }
      __builtin_amdgcn_s_setprio(0);

      __builtin_amdgcn_s_barrier();  // buf (kt)%3 may be overwritten next iter

      if (kt + 1 < nkt) {
#pragma unroll
        for (int tt = 0; tt < 4; ++tt) s_cur[tt] = s_nx[tt];
      }
    }

    __syncthreads();               // phase boundary: drain before restage

    // final l reduce across the 4 lg-groups sharing q = li
    l_r += __shfl_xor(l_r, 16);
    l_r += __shfl_xor(l_r, 32);
    const float inv = 1.0f / l_r;
    const int qg = b * 2048 + qrow + li;
#pragma unroll
    for (int dt = 0; dt < 4; ++dt) {
      f32x4 ov = o[dt];
      ov[0] *= inv; ov[1] *= inv; ov[2] *= inv; ov[3] *= inv;
      *(ushort4*)(ctx + (size_t)qg * 1024 + h * 64 + (dt << 4) + (lg << 2)) = pack4(ov);
    }
  }
}

// ---------------------------------------------------------------- launch
extern "C" void kernel_launch(void* const* d_in, const int* in_sizes, int n_in,
                              void* d_out, int out_size, void* d_ws, size_t ws_size,
                              hipStream_t stream) {
  const float* x  = (const float*)d_in[0];
  const float* Wq = (const float*)d_in[1];
  const float* Wk = (const float*)d_in[2];
  const float* Wv = (const float*)d_in[3];
  const float* Wo = (const float*)d_in[4];
  const float* bo = (const float*)d_in[5];
  float* out = (float*)d_out;

  char* ws = (char*)d_ws;
  uint16_t* xb   = (uint16_t*)(ws);                 // 8MB (dead after QKV gemm)
  uint16_t* Wqkv = (uint16_t*)(ws + ( 8u << 20));   // 6MB: Wq|Wk|Wv contiguous
  uint16_t* Wob  = (uint16_t*)(ws + (14u << 20));   // 2MB
  uint16_t* Qb   = (uint16_t*)(ws + (16u << 20));   // 8MB
  uint16_t* Kb   = (uint16_t*)(ws + (24u << 20));   // 8MB
  uint16_t* Vt   = (uint16_t*)(ws + (32u << 20));   // 8MB
  uint16_t* Ctx  = (uint16_t*)(ws);                 // overlays xb

  cvt_all<<<8192, 256, 0, stream>>>(x, Wq, Wk, Wv, Wo, xb, Wqkv, Wob);

  // fused QKV projection: 256x192 tiles, grid 16x16 = 256 blocks (1/CU)
  gemm_qkv<<<dim3(16, 16), 512, 0, stream>>>(xb, Wqkv, Qb, Kb, Vt);

  // attention: 512 blocks (XCD-mapped, causal-paired), 4 waves, QK-ahead pipe
  attn_fwd<<<512, 256, 0, stream>>>(Qb, Kb, Vt, Ctx);

  // output projection + bias: 128x128 tiles, grid 8x32 = 256 blocks (1/CU)
  gemm_out<<<dim3(8, 32), 512, 0, stream>>>(Ctx, Wob, out, bo);
}

// Round 14
// 103.669 us; speedup vs baseline: 1.0965x; 1.0965x over previous
//
#include <hip/hip_runtime.h>
#include <stdint.h>

#define SEQ   2048
#define DEMB  1024
#define NH    16
#define HD    64
#define MROWS 4096   // BS*SEQ

typedef __bf16 bf16x8 __attribute__((ext_vector_type(8)));
typedef __bf16 bf16x4 __attribute__((ext_vector_type(4)));
typedef float  f32x4  __attribute__((ext_vector_type(4)));

#define MFMA(a, b, c) __builtin_amdgcn_mfma_f32_16x16x32_bf16((a), (b), (c), 0, 0, 0)

static __device__ __forceinline__ uint16_t f2bf(float f) {
  union { __bf16 b; uint16_t u; } c;
  c.b = (__bf16)f;
  return c.u;
}

static __device__ __forceinline__ ushort4 pack4(f32x4 f) {
  union { bf16x4 b; ushort4 u; } c;
  c.b[0] = (__bf16)f[0]; c.b[1] = (__bf16)f[1];
  c.b[2] = (__bf16)f[2]; c.b[3] = (__bf16)f[3];
  return c.u;
}

static __device__ __forceinline__ bf16x8 ldb8(const uint16_t* p) {
  union { uint4 i; bf16x8 b; } u;
  u.i = *(const uint4*)p;
  return u.b;
}

static __device__ __forceinline__ void gld_lds16(const uint16_t* g, uint16_t* l) {
  __builtin_amdgcn_global_load_lds(
      (const __attribute__((address_space(1))) uint32_t*)(g),
      (__attribute__((address_space(3))) uint32_t*)(l),
      16, 0, 0);
}

// ---------------------------------------------------------------- fused converts
__global__ __launch_bounds__(256) void cvt_all(const float* __restrict__ x,
                                               const float* __restrict__ wq,
                                               const float* __restrict__ wk,
                                               const float* __restrict__ wv,
                                               const float* __restrict__ wo,
                                               uint16_t* __restrict__ xb,
                                               uint16_t* __restrict__ wqkv,
                                               uint16_t* __restrict__ wob) {
  const int bid = blockIdx.x;
  const float* src; uint16_t* dst; int off;
  if (bid < 4096)      { src = x;  dst = xb;                 off = bid; }
  else if (bid < 5120) { src = wq; dst = wqkv;               off = bid - 4096; }
  else if (bid < 6144) { src = wk; dst = wqkv + (1u << 20);  off = bid - 5120; }
  else if (bid < 7168) { src = wv; dst = wqkv + (2u << 20);  off = bid - 6144; }
  else                 { src = wo; dst = wob;                off = bid - 7168; }
  const int i = (off * 256 + threadIdx.x) * 4;
  float4 v = *(const float4*)(src + i);
  f32x4 f; f[0] = v.x; f[1] = v.y; f[2] = v.z; f[3] = v.w;
  *(ushort4*)(dst + i) = pack4(f);
}

// ---------------------------------------------------------------- QKV GEMM
// (R10 exact: 256x192, BK=64, 8 waves 2Mx4N wave 128x48, grid 16x16 = 1/CU,
// 112 KB double-buffered LDS, conflict-free XOR swizzle, V^T via LDS slab)
__global__ __launch_bounds__(512, 2) void gemm_qkv(const uint16_t* __restrict__ A,
                                                   const uint16_t* __restrict__ B,
                                                   uint16_t* __restrict__ Cq,
                                                   uint16_t* __restrict__ Ck,
                                                   uint16_t* __restrict__ Cvt) {
  constexpr int K = 1024;
  __shared__ uint16_t lds[57344];      // 112 KB

  const int bcol = blockIdx.x * 192;
  const int brow = blockIdx.y << 8;

  const int t  = threadIdx.x;
  const int l  = t & 63;
  const int li = l & 15, lg = l >> 4;
  const int w  = t >> 6;               // 0..7
  const int wm = w >> 2;               // row half: wm*128
  const int wn = w & 3;                // col quarter: wn*48

  const int srow = t >> 3;
  const int scol = ((t & 7) ^ (srow & 7)) << 3;
  const uint16_t* gA = A + (size_t)(brow + srow) * K + scol;
  const uint16_t* gB = B + (size_t)(bcol + srow) * K + scol;

  auto stage = [&](int buf, int k0) {
    uint16_t* as = lds + buf * 16384;
    uint16_t* bs = lds + 32768 + buf * 12288;
    gld_lds16(gA + k0,                    as + t * 8);
    gld_lds16(gA + (size_t)64 * K + k0,   as + 4096 + t * 8);
    gld_lds16(gA + (size_t)128 * K + k0,  as + 8192 + t * 8);
    gld_lds16(gA + (size_t)192 * K + k0,  as + 12288 + t * 8);
    gld_lds16(gB + k0,                    bs + t * 8);
    gld_lds16(gB + (size_t)64 * K + k0,   bs + 4096 + t * 8);
    gld_lds16(gB + (size_t)128 * K + k0,  bs + 8192 + t * 8);
  };

  const int sw = li & 7;
  auto ldA = [&](int buf, int kh, int fi) {
    const int row = wm * 128 + fi * 16 + li;
    return ldb8(&lds[buf * 16384 + (row << 6) + ((((kh << 2) + lg) ^ sw) << 3)]);
  };
  auto ldB = [&](int buf, int kh, int ni) {
    const int row = wn * 48 + ni * 16 + li;
    return ldb8(&lds[32768 + buf * 12288 + (row << 6) + ((((kh << 2) + lg) ^ sw) << 3)]);
  };

  f32x4 acc[8][3] = {};

  stage(0, 0);
  __syncthreads();
  int cur = 0;

  for (int k0 = 0; k0 < K; k0 += 64) {
    if (k0 + 64 < K) stage(cur ^ 1, k0 + 64);

#pragma unroll
    for (int kh = 0; kh < 2; ++kh) {
      bf16x8 af[8], bfr[3];
#pragma unroll
      for (int ni = 0; ni < 3; ++ni) bfr[ni] = ldB(cur, kh, ni);
#pragma unroll
      for (int fi = 0; fi < 8; ++fi) af[fi] = ldA(cur, kh, fi);
      __builtin_amdgcn_s_setprio(1);
#pragma unroll
      for (int fi = 0; fi < 8; ++fi)
#pragma unroll
        for (int ni = 0; ni < 3; ++ni)
          acc[fi][ni] = MFMA(af[fi], bfr[ni], acc[fi][ni]);
      __builtin_amdgcn_s_setprio(0);
    }

    __syncthreads();
    cur ^= 1;
  }

  // ---- epilogue. Q/K: direct stores. V: per-wave LDS transpose -> coalesced.
  uint16_t* slab = lds + w * 6800;
  bool anyV = false;

#pragma unroll
  for (int mi = 0; mi < 8; ++mi) {
#pragma unroll
    for (int ni = 0; ni < 3; ++ni) {
      const int col = bcol + wn * 48 + ni * 16 + li;
      const int row = brow + wm * 128 + mi * 16 + lg * 4;   // + r
      if (col < 1024) {
#pragma unroll
        for (int r = 0; r < 4; ++r)
          Cq[(size_t)(row + r) * 1024 + col] = f2bf(acc[mi][ni][r] * 0.18033688f);
      } else if (col < 2048) {
#pragma unroll
        for (int r = 0; r < 4; ++r)
          Ck[(size_t)(row + r) * 1024 + (col - 1024)] = f2bf(acc[mi][ni][r]);
      } else {
        anyV = true;
        *(ushort4*)&slab[(ni * 16 + li) * 136 + mi * 16 + lg * 4] = pack4(acc[mi][ni]);
      }
    }
  }

  if (anyV) {
    asm volatile("s_waitcnt lgkmcnt(0)" ::: "memory");
    const int m0 = brow + wm * 128;
    const size_t mbase = (size_t)((m0 >> 11) << 10) * 2048 + (m0 & 2047);
#pragma unroll
    for (int cc = 0; cc < 12; ++cc) {
      const int c_loc = cc * 4 + lg;
      const int cglob = bcol + wn * 48 + c_loc;
      if (cglob >= 2048) {
        const int c = cglob - 2048;
        uint4 v = *(const uint4*)&slab[c_loc * 136 + li * 8];
        *(uint4*)(Cvt + (size_t)c * 2048 + mbase + li * 8) = v;
      }
    }
  }
}

// ---------------------------------------------------------------- out projection
// (R10 exact: 128x128, BK=64, 8 waves wave 64x32, grid 8x32 = 1/CU)
__global__ __launch_bounds__(512, 2) void gemm_out(const uint16_t* __restrict__ A,
                                                   const uint16_t* __restrict__ B,
                                                   float* __restrict__ Cf,
                                                   const float* __restrict__ bias) {
  constexpr int K = 1024;
  __shared__ uint16_t As[2][128 * 64];
  __shared__ uint16_t Bs[2][128 * 64];

  const int bcol = blockIdx.x << 7;
  const int brow = blockIdx.y << 7;

  const int t  = threadIdx.x;
  const int l  = t & 63;
  const int li = l & 15, lg = l >> 4;
  const int w  = t >> 6;
  const int wm = w >> 2;
  const int wn = w & 3;

  const int srow = t >> 3;
  const int scol = ((t & 7) ^ (srow & 7)) << 3;
  const uint16_t* gA = A + (size_t)(brow + srow) * K + scol;
  const uint16_t* gB = B + (size_t)(bcol + srow) * K + scol;

  auto stage = [&](int buf, int k0) {
    gld_lds16(gA + k0,                  &As[buf][t * 8]);
    gld_lds16(gA + (size_t)64 * K + k0, &As[buf][4096 + t * 8]);
    gld_lds16(gB + k0,                  &Bs[buf][t * 8]);
    gld_lds16(gB + (size_t)64 * K + k0, &Bs[buf][4096 + t * 8]);
  };

  const int sw = li & 7;
  auto ldA = [&](int buf, int kh, int fi) {
    const int row = wm * 64 + fi * 16 + li;
    return ldb8(&As[buf][(row << 6) + ((((kh << 2) + lg) ^ sw) << 3)]);
  };
  auto ldB = [&](int buf, int kh, int ni) {
    const int row = wn * 32 + ni * 16 + li;
    return ldb8(&Bs[buf][(row << 6) + ((((kh << 2) + lg) ^ sw) << 3)]);
  };

  f32x4 acc[4][2] = {};

  stage(0, 0);
  __syncthreads();
  int cur = 0;

  for (int k0 = 0; k0 < K; k0 += 64) {
    if (k0 + 64 < K) stage(cur ^ 1, k0 + 64);

#pragma unroll
    for (int kh = 0; kh < 2; ++kh) {
      bf16x8 af[4], bfr[2];
#pragma unroll
      for (int ni = 0; ni < 2; ++ni) bfr[ni] = ldB(cur, kh, ni);
#pragma unroll
      for (int fi = 0; fi < 4; ++fi) af[fi] = ldA(cur, kh, fi);
      __builtin_amdgcn_s_setprio(1);
#pragma unroll
      for (int fi = 0; fi < 4; ++fi)
#pragma unroll
        for (int ni = 0; ni < 2; ++ni)
          acc[fi][ni] = MFMA(af[fi], bfr[ni], acc[fi][ni]);
      __builtin_amdgcn_s_setprio(0);
    }

    __syncthreads();
    cur ^= 1;
  }

#pragma unroll
  for (int mi = 0; mi < 4; ++mi) {
#pragma unroll
    for (int ni = 0; ni < 2; ++ni) {
      const int row = brow + wm * 64 + mi * 16 + lg * 4;
      const int col = bcol + wn * 32 + ni * 16 + li;
      const float bv = bias[col];
#pragma unroll
      for (int r = 0; r < 4; ++r)
        Cf[(size_t)(row + r) * 1024 + col] = acc[mi][ni][r] + bv;
    }
  }
}

// ---------------------------------------------------------------- flash attention
// R10 inner body (4-wave, QBLK=64, double-buffered swizzled K/V, no-max exp2
// softmax, setprio). R14 change: ONE q-block per block, 1024 blocks total
// (heavy qbl dispatched first, XCD head-grouped) -> 3 blocks/CU resident +
// 256-block queue. Oversubscription hides the per-tile serial chain that
// exact-residency (R8-R13, 2/CU) exposed.
__global__ __launch_bounds__(256, 3) void attn_fwd(const uint16_t* __restrict__ Q,
                                                   const uint16_t* __restrict__ K,
                                                   const uint16_t* __restrict__ Vt,
                                                   uint16_t* __restrict__ ctx) {
  const int id   = blockIdx.x;               // 0..1023; id&7 = XCD
  const int rank = id >> 3;                  // 0..127
  const int bh   = (id & 7) * 4 + (rank >> 5);
  const int qbl  = 31 - (rank & 31);         // heavy q-blocks first
  const int b = bh >> 4, h = bh & 15;

  const int t  = threadIdx.x;
  const int w  = t >> 6, l = t & 63;
  const int li = l & 15, lg = l >> 4;

  __shared__ uint16_t Kl[2][64 * 64];   // 8KB x2 (key, d), swizzled
  __shared__ uint16_t Vl[2][64 * 64];   // 8KB x2 (d, key), swizzled
  __shared__ uint16_t P[4][16][72];     // per-wave P slab

  const uint16_t* Kg = K + (size_t)(b * 2048) * 1024 + h * 64;
  const uint16_t* Vg = Vt + (size_t)(b * 1024 + h * 64) * 2048;

  const int srow = t >> 3;                          // 0..31
  const int scol = ((t & 7) * 8) ^ ((srow & 7) * 8);

  auto stage = [&](int buf, int kt2) {
    const int kb2 = kt2 << 6;
    gld_lds16(Kg + (size_t)(kb2 + srow) * 1024 + scol,      &Kl[buf][t * 8]);
    gld_lds16(Kg + (size_t)(kb2 + 32 + srow) * 1024 + scol, &Kl[buf][2048 + t * 8]);
    gld_lds16(Vg + (size_t)srow * 2048 + kb2 + scol,        &Vl[buf][t * 8]);
    gld_lds16(Vg + (size_t)(32 + srow) * 2048 + kb2 + scol, &Vl[buf][2048 + t * 8]);
  };

  const int fsw = (li & 7) * 8;

  const int qrow = (qbl << 6) + (w << 4);
  const uint16_t* qp = Q + (size_t)(b * 2048 + qrow + li) * 1024 + h * 64 + lg * 8;
  const bf16x8 q0 = ldb8(qp);
  const bf16x8 q1 = ldb8(qp + 32);

  f32x4 o[4] = {};                     // O[d = dt*16 + lg*4 + r][q = li]
  float l_r = 0.f;

  stage(0, 0);
  __syncthreads();
  int cur = 0;

  for (int kt = 0; kt <= qbl; ++kt) {
    if (kt < qbl) stage(cur ^ 1, kt + 1);

    const uint16_t* Kc = &Kl[cur][0];
    const uint16_t* Vc = &Vl[cur][0];

    // QK^T swapped: s[tt][r] = S[key = kt*64+tt*16+lg*4+r][q = qrow+li]
    f32x4 s[4];
    __builtin_amdgcn_s_setprio(1);
#pragma unroll
    for (int tt = 0; tt < 4; ++tt) {
      const uint16_t* kr = Kc + (tt * 16 + li) * 64;
      f32x4 z = {};
      z = MFMA(ldb8(kr + ((lg * 8) ^ fsw)), q0, z);
      z = MFMA(ldb8(kr + ((32 + lg * 8) ^ fsw)), q1, z);
      s[tt] = z;
    }
    __builtin_amdgcn_s_setprio(0);

    // V fragments: lane holds V[d = dt*16 + li][key = half*32 + lg*8 + j]
    bf16x8 vf[4][2];
#pragma unroll
    for (int dt = 0; dt < 4; ++dt) {
      const uint16_t* vr = Vc + (dt * 16 + li) * 64;
      vf[dt][0] = ldb8(vr + ((lg * 8) ^ fsw));
      vf[dt][1] = ldb8(vr + ((32 + lg * 8) ^ fsw));
    }

    if (kt == qbl) {   // diagonal tile: causal mask -> exp2 gives exact 0
      const int qloc = (w << 4) + li;
#pragma unroll
      for (int tt = 0; tt < 4; ++tt) {
        const int key = (tt << 4) + (lg << 2);
#pragma unroll
        for (int r = 0; r < 4; ++r)
          if (key + r > qloc) s[tt][r] = -1e30f;
      }
    }

    // ---- no-max softmax: P = exp2(s), per-lane partial l
    float lsum = 0.f;
    ushort4 pk[4];
#pragma unroll
    for (int tt = 0; tt < 4; ++tt) {
      f32x4 p;
      p[0] = __builtin_amdgcn_exp2f(s[tt][0]);
      p[1] = __builtin_amdgcn_exp2f(s[tt][1]);
      p[2] = __builtin_amdgcn_exp2f(s[tt][2]);
      p[3] = __builtin_amdgcn_exp2f(s[tt][3]);
      lsum += (p[0] + p[1]) + (p[2] + p[3]);
      pk[tt] = pack4(p);
    }
    l_r += lsum;

    // ---- P relayout via per-wave LDS slab
#pragma unroll
    for (int tt = 0; tt < 4; ++tt)
      *(ushort4*)&P[w][li][(tt << 4) + (lg << 2)] = pk[tt];
    asm volatile("s_waitcnt lgkmcnt(0)" ::: "memory");

    const bf16x8 pb0 = ldb8(&P[w][li][lg * 8]);
    const bf16x8 pb1 = ldb8(&P[w][li][32 + lg * 8]);
    __builtin_amdgcn_s_setprio(1);
#pragma unroll
    for (int dt = 0; dt < 4; ++dt) {
      o[dt] = MFMA(vf[dt][0], pb0, o[dt]);
      o[dt] = MFMA(vf[dt][1], pb1, o[dt]);
    }
    __builtin_amdgcn_s_setprio(0);

    __syncthreads();
    cur ^= 1;
  }

  // final l reduce across the 4 lg-groups sharing q = li
  l_r += __shfl_xor(l_r, 16);
  l_r += __shfl_xor(l_r, 32);
  const float inv = 1.0f / l_r;
  const int qg = b * 2048 + qrow + li;
#pragma unroll
  for (int dt = 0; dt < 4; ++dt) {
    f32x4 ov = o[dt];
    ov[0] *= inv; ov[1] *= inv; ov[2] *= inv; ov[3] *= inv;
    *(ushort4*)(ctx + (size_t)qg * 1024 + h * 64 + (dt << 4) + (lg << 2)) = pack4(ov);
  }
}

// ---------------------------------------------------------------- launch
extern "C" void kernel_launch(void* const* d_in, const int* in_sizes, int n_in,
                              void* d_out, int out_size, void* d_ws, size_t ws_size,
                              hipStream_t stream) {
  const float* x  = (const float*)d_in[0];
  const float* Wq = (const float*)d_in[1];
  const float* Wk = (const float*)d_in[2];
  const float* Wv = (const float*)d_in[3];
  const float* Wo = (const float*)d_in[4];
  const float* bo = (const float*)d_in[5];
  float* out = (float*)d_out;

  char* ws = (char*)d_ws;
  uint16_t* xb   = (uint16_t*)(ws);                 // 8MB (dead after QKV gemm)
  uint16_t* Wqkv = (uint16_t*)(ws + ( 8u << 20));   // 6MB: Wq|Wk|Wv contiguous
  uint16_t* Wob  = (uint16_t*)(ws + (14u << 20));   // 2MB
  uint16_t* Qb   = (uint16_t*)(ws + (16u << 20));   // 8MB
  uint16_t* Kb   = (uint16_t*)(ws + (24u << 20));   // 8MB
  uint16_t* Vt   = (uint16_t*)(ws + (32u << 20));   // 8MB
  uint16_t* Ctx  = (uint16_t*)(ws);                 // overlays xb

  cvt_all<<<8192, 256, 0, stream>>>(x, Wq, Wk, Wv, Wo, xb, Wqkv, Wob);

  // fused QKV projection: 256x192 tiles, grid 16x16 = 256 blocks (1/CU)
  gemm_qkv<<<dim3(16, 16), 512, 0, stream>>>(xb, Wqkv, Qb, Kb, Vt);

  // attention: 1024 blocks (one q-block each, heavy-first, XCD-mapped)
  attn_fwd<<<1024, 256, 0, stream>>>(Qb, Kb, Vt, Ctx);

  // output projection + bias: 128x128 tiles, grid 8x32 = 256 blocks (1/CU)
  gemm_out<<<dim3(8, 32), 512, 0, stream>>>(Ctx, Wob, out, bo);
}